// Round 1
// 590.699 us; speedup vs baseline: 1.0186x; 1.0186x over previous
//
#include <hip/hip_runtime.h>
#include <stdint.h>

// HungarianMatcher on MI355X — round 5: cut mfma_kernel VALU.
// Round 4 profile model: mfma k-loop is VALU-bound (~1460 SIMD-cyc/k-iter/wave
// vs ~40 cyc of MFMA). ~65% of that is (a) hand-rolled fp32->bf16 bit-twiddle
// plus per-short8-element insert ops and (b) per-bit cndmask B expansion.
// This round:
//   * fragments built as 4x uint32 words via native v_cvt_pk_bf16_f32 (RNE,
//     bit-identical to old f2bf) through a union -> no insert ops.
//   * B bits expanded a packed PAIR at a time: ((a&1)|((c&1)<<16))*0x3F80.
//   * pack_kernel: 2 output px per thread via one float4 load (contiguous
//     1 KB/wave-instr), uint2 packed store.
// Hungarian kernel unchanged (latency-bound, ~50-100 shuffle-reduce iters).

#define BATCH 8
#define NQ    100
#define NT    32
#define HWP   65536      // 256*256
#define NCLS  81
#define BIGV  1.0e6
#define MPAD  112        // 7*16
#define MTILES 7
#define KSPLIT 16
#define KC (HWP / KSPLIT)   // 4096 px per block
#define KW (KC / 4)         // 1024 px per wave
#define NITER (KW / 64)     // 16 k-iters of 64 px

typedef __attribute__((ext_vector_type(8))) short short8;
typedef __attribute__((ext_vector_type(4))) float f32x4;

union FragU { short8 s; uint32_t w[4]; };

__device__ inline uint32_t cvt_pk_bf16(float lo, float hi) {  // RNE packed cvt
    uint32_t r;
    asm("v_cvt_pk_bf16_f32 %0, %1, %2" : "=v"(r) : "v"(lo), "v"(hi));
    return r;
}

// expand bit r (lo halves) / bit r+16 (hi halves) of two packed words into
// two bf16-pair words: {bf16(bit), bf16(bit)} with value 1.0 (0x3F80) or 0.
__device__ inline void bpair(uint32_t wlo, uint32_t whi, int r,
                             uint32_t& lofrag, uint32_t& hifrag) {
    uint32_t a = wlo >> r;
    uint32_t c = whi >> r;
    lofrag = ((a & 1u) | ((c & 1u) << 16)) * 0x3F80u;
    hifrag = (((a >> 16) & 1u) | (((c >> 16) & 1u) << 16)) * 0x3F80u;
}

// -------------------------------------------------------------------------
// 2 output px per thread: one float4 covers input cols 4xp..4xp+3 -> even
// samples at elems 0 and 2. Fully coalesced 16 B/lane loads, uint2 store.
__global__ __launch_bounds__(256) void pack_kernel(const float* __restrict__ tmask,
                                                   uint32_t* __restrict__ packed,
                                                   int* __restrict__ tm_counts) {
    int idx = blockIdx.x * 256 + threadIdx.x;   // BATCH * HWP/2 threads
    int b  = idx >> 15;                         // 32768 pairs per batch
    int pp = idx & 32767;
    int y  = pp >> 7;                           // out row (in row = 2y)
    int xp = pp & 127;                          // pair: out x = 2xp, 2xp+1
    const float* base = tmask + (size_t)b * NT * 262144 + (size_t)(2 * y) * 512 + 4 * xp;
    uint32_t w0 = 0, w1 = 0;
#pragma unroll
    for (int t = 0; t < NT; ++t) {
        float4 v = *(const float4*)(base + (size_t)t * 262144);
        w0 |= (v.x > 0.5f ? 1u : 0u) << t;
        w1 |= (v.z > 0.5f ? 1u : 0u) << t;
    }
    int p0 = y * 256 + 2 * xp;
    *(uint2*)(packed + (size_t)b * HWP + p0) = make_uint2(w0, w1);

    int lane = threadIdx.x & 63;
    int mycnt = 0;
#pragma unroll
    for (int t = 0; t < NT; ++t) {
        unsigned long long m0 = __ballot((w0 >> t) & 1u);
        unsigned long long m1 = __ballot((w1 >> t) & 1u);
        if (lane == t) mycnt = __popcll(m0) + __popcll(m1);
    }
    if (lane < NT) atomicAdd(&tm_counts[b * NT + lane], mycnt);
}

// -------------------------------------------------------------------------
// accd: [2][BATCH][MPAD][32] fp32 (dot_pm, dot_sig); accs: [2][BATCH][MPAD]
__global__ __launch_bounds__(256) void mfma_kernel(const float* __restrict__ pmask,
                                                   const uint32_t* __restrict__ packed,
                                                   float* __restrict__ accd,
                                                   float* __restrict__ accs) {
    const int kblk = blockIdx.x;
    const int mt   = blockIdx.y;
    const int b    = blockIdx.z;
    const int tid  = threadIdx.x;
    const int wv   = tid >> 6, lane = tid & 63;
    const int m0   = mt * 16;
    const int q    = lane >> 4;    // 0..3  (k-quad)
    const int r    = lane & 15;    // 0..15 (A row / B target)

    __shared__ float Cred[8][16][32];

    int mrow = m0 + r; if (mrow > NQ - 1) mrow = NQ - 1;   // pad rows duplicate row 99
    const float* Arow = pmask + (size_t)b * NQ * HWP + (size_t)mrow * HWP;
    const uint32_t* pkb = packed + (size_t)b * HWP;
    const int kbase0 = kblk * KC + wv * KW;

    f32x4 Cpm0 = {0,0,0,0}, Cpm1 = {0,0,0,0}, Csg0 = {0,0,0,0}, Csg1 = {0,0,0,0};
    float rsp = 0.f, rsg = 0.f;

    for (int ki = 0; ki < NITER; ++ki) {
        const int kb = kbase0 + ki * 64;
        // --- direct fragment loads (no LDS) ---
        const float4 va0 = *(const float4*)(Arow + kb + q * 8);
        const float4 va1 = *(const float4*)(Arow + kb + q * 8 + 4);
        const float4 va2 = *(const float4*)(Arow + kb + 32 + q * 8);
        const float4 va3 = *(const float4*)(Arow + kb + 32 + q * 8 + 4);
        const uint4  wb0 = *(const uint4*)(pkb + kb + q * 8);
        const uint4  wb1 = *(const uint4*)(pkb + kb + q * 8 + 4);
        const uint4  wb2 = *(const uint4*)(pkb + kb + 32 + q * 8);
        const uint4  wb3 = *(const uint4*)(pkb + kb + 32 + q * 8 + 4);

        FragU a0, a1, g0, g1;
        auto proc4 = [&](const float4& v, uint32_t* aw, uint32_t* gw) {
            float sg[4];
#pragma unroll
            for (int e = 0; e < 4; ++e) {
                float pv = (&v.x)[e];
                float ax = fabsf(pv);
                float en = __expf(-ax);
                float one_en = 1.0f + en;
                float inv = __builtin_amdgcn_rcpf(one_en);
                float sig = (pv >= 0.f) ? inv : en * inv;
                float sp  = fmaxf(pv, 0.f) + __logf(one_en);
                rsp += sp; rsg += sig;
                sg[e] = sig;
            }
            aw[0] = cvt_pk_bf16(v.x, v.y);
            aw[1] = cvt_pk_bf16(v.z, v.w);
            gw[0] = cvt_pk_bf16(sg[0], sg[1]);
            gw[1] = cvt_pk_bf16(sg[2], sg[3]);
        };
        proc4(va0, &a0.w[0], &g0.w[0]);
        proc4(va1, &a0.w[2], &g0.w[2]);
        proc4(va2, &a1.w[0], &g1.w[0]);
        proc4(va3, &a1.w[2], &g1.w[2]);

        FragU b00, b01, b10, b11;
        bpair(wb0.x, wb0.y, r, b00.w[0], b10.w[0]);
        bpair(wb0.z, wb0.w, r, b00.w[1], b10.w[1]);
        bpair(wb1.x, wb1.y, r, b00.w[2], b10.w[2]);
        bpair(wb1.z, wb1.w, r, b00.w[3], b10.w[3]);
        bpair(wb2.x, wb2.y, r, b01.w[0], b11.w[0]);
        bpair(wb2.z, wb2.w, r, b01.w[1], b11.w[1]);
        bpair(wb3.x, wb3.y, r, b01.w[2], b11.w[2]);
        bpair(wb3.z, wb3.w, r, b01.w[3], b11.w[3]);

        Cpm0 = __builtin_amdgcn_mfma_f32_16x16x32_bf16(a0.s, b00.s, Cpm0, 0, 0, 0);
        Cpm0 = __builtin_amdgcn_mfma_f32_16x16x32_bf16(a1.s, b01.s, Cpm0, 0, 0, 0);
        Cpm1 = __builtin_amdgcn_mfma_f32_16x16x32_bf16(a0.s, b10.s, Cpm1, 0, 0, 0);
        Cpm1 = __builtin_amdgcn_mfma_f32_16x16x32_bf16(a1.s, b11.s, Cpm1, 0, 0, 0);
        Csg0 = __builtin_amdgcn_mfma_f32_16x16x32_bf16(g0.s, b00.s, Csg0, 0, 0, 0);
        Csg0 = __builtin_amdgcn_mfma_f32_16x16x32_bf16(g1.s, b01.s, Csg0, 0, 0, 0);
        Csg1 = __builtin_amdgcn_mfma_f32_16x16x32_bf16(g0.s, b10.s, Csg1, 0, 0, 0);
        Csg1 = __builtin_amdgcn_mfma_f32_16x16x32_bf16(g1.s, b11.s, Csg1, 0, 0, 0);
    }

    // row sums: reduce across the 4 k-quads (lane bits 4,5) -> q==0 lanes
    rsp += __shfl_xor(rsp, 16, 64);
    rsp += __shfl_xor(rsp, 32, 64);
    rsg += __shfl_xor(rsg, 16, 64);
    rsg += __shfl_xor(rsg, 32, 64);
    if (q == 0 && m0 + r < NQ) {
        atomicAdd(&accs[(size_t)b * MPAD + m0 + r], rsp);
        atomicAdd(&accs[(size_t)(BATCH + b) * MPAD + m0 + r], rsg);
    }

    // C/D layout: col = lane&15 (target), row = (lane>>4)*4 + e (query)
#pragma unroll
    for (int e = 0; e < 4; ++e) {
        const int m = q * 4 + e;
        Cred[wv * 2 + 0][m][r]      = Cpm0[e];
        Cred[wv * 2 + 0][m][16 + r] = Cpm1[e];
        Cred[wv * 2 + 1][m][r]      = Csg0[e];
        Cred[wv * 2 + 1][m][16 + r] = Csg1[e];
    }
    __syncthreads();
    for (int idx = tid; idx < 1024; idx += 256) {
        const int type = idx >> 9, rem = idx & 511, m = rem >> 5, n = rem & 31;
        float s = Cred[0 + type][m][n] + Cred[2 + type][m][n]
                + Cred[4 + type][m][n] + Cred[6 + type][m][n];
        const int gm = m0 + m;
        if (gm < NQ)
            atomicAdd(&accd[(size_t)(type * BATCH + b) * MPAD * 32 + (size_t)gm * 32 + n], s);
    }
}

// -------------------------------------------------------------------------
// Finalize cost matrix + exact single-wave JV Hungarian.
__global__ __launch_bounds__(64) void hungarian_kernel(const float* __restrict__ logits,
                                                       const int* __restrict__ labels,
                                                       const float* __restrict__ accd,
                                                       const float* __restrict__ accs,
                                                       const int* __restrict__ tm_counts,
                                                       int* __restrict__ out) {
    const int b = blockIdx.x;
    const int lane = threadIdx.x;

    __shared__ double Ct[NT][NQ];
    __shared__ double u[NT + 1];
    __shared__ float smx[NQ], ssm[NQ];
    __shared__ float tcs[NT];
    __shared__ int lab[NT];

    if (lane < NT) { tcs[lane] = (float)tm_counts[b * NT + lane]; lab[lane] = labels[b * NT + lane]; }
    for (int n = lane; n < NQ; n += 64) {
        const float* lg = logits + (size_t)(b * NQ + n) * NCLS;
        float mx = -1e30f;
        for (int c = 0; c < NCLS; ++c) mx = fmaxf(mx, lg[c]);
        float s = 0.f;
        for (int c = 0; c < NCLS; ++c) s += __expf(lg[c] - mx);
        smx[n] = mx; ssm[n] = s;
    }
    if (lane <= NT) u[lane] = 0.0;
    __syncthreads();
    for (int idx = lane; idx < NQ * NT; idx += 64) {
        const int t2 = idx & 31, q2 = idx >> 5;
        float dpm = accd[(size_t)b * MPAD * 32 + q2 * 32 + t2];
        float dsg = accd[(size_t)(BATCH + b) * MPAD * 32 + q2 * 32 + t2];
        float ssp = accs[(size_t)b * MPAD + q2];
        float ssg = accs[(size_t)(BATCH + b) * MPAD + q2];
        float lg = logits[(size_t)(b * NQ + q2) * NCLS + lab[t2]];
        float prob = __expf(lg - smx[q2]) / ssm[q2];
        float c = -prob + (ssp - dpm) * (1.0f / (float)HWP)
                + 1.0f - (2.0f * dsg + 1.0f) / (ssg + tcs[t2] + 1.0f);
        if (isnan(c)) c = (float)BIGV;
        else if (isinf(c)) c = (c > 0.f) ? (float)BIGV : -(float)BIGV;
        Ct[t2][q2] = (double)c;
    }
    __syncthreads();

    const int c0 = lane + 1;
    const bool valid1 = (lane < NQ - 64);
    const int c1 = lane + 65;
    const int cidx1 = valid1 ? (lane + 64) : 0;

    double v0 = 0.0, v1 = 0.0;
    int p0 = 0, p1 = 0;
    double u_reg = 0.0;                       // mirror of u[lane] (lanes 0..32)

    for (int i = 1; i <= NT; ++i) {
        double minv0 = 1e300, minv1 = 1e300;
        int way0 = 0, way1 = 0;
        bool used0 = false, used1 = !valid1;
        double du0 = 0.0, du1 = 0.0, dtot = 0.0;
        int j0 = 0, i0 = i;
        int jfin = 0;

        for (int guard = 0; guard < 160; ++guard) {
            double u_i0 = __shfl(u_reg, i0, 64);     // reg-mirror broadcast
            double cur0 = Ct[i0 - 1][lane] - u_i0 - v0;
            if (!used0 && cur0 < minv0) { minv0 = cur0; way0 = j0; }
            double cur1 = Ct[i0 - 1][cidx1] - u_i0 - v1;
            if (!used1 && cur1 < minv1) { minv1 = cur1; way1 = j0; }
            double bv = 1e301; int bj = 1 << 20;
            if (!used0) { bv = minv0; bj = c0; }
            if (!used1 && minv1 < bv) { bv = minv1; bj = c1; }
#pragma unroll
            for (int s = 32; s > 0; s >>= 1) {
                double ov = __shfl_down(bv, s, 64);
                int    oj = __shfl_down(bj, s, 64);
                if (ov < bv || (ov == bv && oj < bj)) { bv = ov; bj = oj; }
            }
            double delta = __shfl(bv, 0, 64);
            int j1 = __shfl(bj, 0, 64);
            dtot += delta;
            if (used0) { v0 -= delta; du0 += delta; } else { minv0 -= delta; }
            if (valid1) {
                if (used1) { v1 -= delta; du1 += delta; } else { minv1 -= delta; }
            }
            if (c0 == j1) used0 = true;
            if (valid1 && c1 == j1) used1 = true;
            int src = (j1 - 1) & 63, slot = (j1 - 1) >> 6;
            int pa = __shfl(p0, src, 64), pb = __shfl(p1, src, 64);
            int pj1 = slot ? pb : pa;
            if (pj1 == 0) { jfin = j1; break; }
            j0 = j1; i0 = pj1;
        }

        // deferred u updates (distinct rows across used cols -> race-free)
        if (used0 && p0 != 0) u[p0] += du0;
        if (valid1 && used1 && p1 != 0) u[p1] += du1;
        if (lane == 0) u[i] += dtot;

        int jj = jfin;
        for (int guard = 0; guard < 160 && jj != 0; ++guard) {
            int src = (jj - 1) & 63, slot = (jj - 1) >> 6;
            int wa = __shfl(way0, src, 64), wb = __shfl(way1, src, 64);
            int jprev = slot ? wb : wa;
            int pnew;
            if (jprev == 0) pnew = i;
            else {
                int s2 = (jprev - 1) & 63, sl2 = (jprev - 1) >> 6;
                int pa = __shfl(p0, s2, 64), pb = __shfl(p1, s2, 64);
                pnew = sl2 ? pb : pa;
            }
            if (c0 == jj) p0 = pnew;
            if (valid1 && c1 == jj) p1 = pnew;
            jj = jprev;
        }
        __syncthreads();
        u_reg = (lane <= NT) ? u[lane] : 0.0;   // refresh mirror once per row
    }

    unsigned long long m0 = __ballot(p0 != 0);
    unsigned long long m1 = __ballot(valid1 && p1 != 0);
    int base = b * NT;
    if (p0 != 0) {
        int rank = __popcll(m0 & ((1ull << lane) - 1ull));
        out[base + rank] = c0 - 1;
        out[BATCH * NT + base + rank] = p0 - 1;
    }
    if (valid1 && p1 != 0) {
        int rank = __popcll(m0) + __popcll(m1 & ((1ull << lane) - 1ull));
        out[base + rank] = c1 - 1;
        out[BATCH * NT + base + rank] = p1 - 1;
    }
}

// -------------------------------------------------------------------------
extern "C" void kernel_launch(void* const* d_in, const int* in_sizes, int n_in,
                              void* d_out, int out_size, void* d_ws, size_t ws_size,
                              hipStream_t stream) {
    const float* logits = (const float*)d_in[0];   // [8,100,81]
    const float* pmasks = (const float*)d_in[1];   // [8,100,256,256]
    const float* tmasks = (const float*)d_in[2];   // [8,32,512,512]
    const int*   labels = (const int*)d_in[3];     // [8,32]

    uint8_t* ws = (uint8_t*)d_ws;
    uint32_t* packed = (uint32_t*)ws;                       // 2 MiB
    uint8_t* zbase = ws + (size_t)BATCH * HWP * 4;
    int* tm_counts = (int*)zbase;                           // 1 KiB
    float* accd = (float*)(zbase + 1024);                   // 229376 B
    float* accs = (float*)(zbase + 1024 + 229376);          // 7168 B
    const size_t ztotal = 1024 + 229376 + 7168;

    int* out = (int*)d_out;   // int32: src [8,32] then tgt [8,32]

    hipMemsetAsync(zbase, 0, ztotal, stream);
    pack_kernel<<<BATCH * HWP / 512, 256, 0, stream>>>(tmasks, packed, tm_counts);
    mfma_kernel<<<dim3(KSPLIT, MTILES, BATCH), 256, 0, stream>>>(pmasks, packed, accd, accs);
    hungarian_kernel<<<BATCH, 64, 0, stream>>>(logits, labels, accd, accs, tm_counts, out);
}